// Round 5
// baseline (566.385 us; speedup 1.0000x reference)
//
#include <hip/hip_runtime.h>
#include <cstdint>
#include <cstddef>

typedef __attribute__((ext_vector_type(8))) short bf16x8;
typedef __attribute__((ext_vector_type(4))) short bf16x4;
typedef __attribute__((ext_vector_type(4))) float f32x4;

__device__ __forceinline__ unsigned short f2bf(float f) {
    union { float f; unsigned int u; } v; v.f = f;
    unsigned int r = v.u + 0x7FFFu + ((v.u >> 16) & 1u);
    return (unsigned short)(r >> 16);
}
__device__ __forceinline__ unsigned int pk2(float a, float b) {
    return (unsigned int)f2bf(a) | ((unsigned int)f2bf(b) << 16);
}
// pack two f32 -> bf16x2 in one VALU op when the HW builtin exists
__device__ __forceinline__ unsigned int pkpair(float a, float b) {
#if __has_builtin(__builtin_amdgcn_cvt_pk_bf16_f32)
    auto r = __builtin_amdgcn_cvt_pk_bf16_f32(a, b);
    return __builtin_bit_cast(unsigned int, r);
#else
    unsigned int ua = __builtin_bit_cast(unsigned int, a) + 0x8000u;
    unsigned int ub = __builtin_bit_cast(unsigned int, b) + 0x8000u;
    return __builtin_amdgcn_perm(ub, ua, 0x07060302u);  // [a_hi16 | b_hi16<<16]
#endif
}

// async global->LDS, 16B per lane (global_load_lds_dwordx4).
// LDS dest semantics: wave-uniform base + lane*16 (m104/m108).
typedef __attribute__((address_space(1))) void gvoid;
typedef __attribute__((address_space(3))) void svoid;
__device__ __forceinline__ void ld16_lds(const void* g, void* l) {
    __builtin_amdgcn_global_load_lds((gvoid*)g, (svoid*)l, 16, 0, 0);
}

#define QSCALE 0.1803368801111204f  // 0.125 * log2(e): folded into Q so scores feed exp2

// ---------------------------------------------------------------------------
// Merged preprocessing (one launch instead of three):
//   blocks [0,12288):    fp32->bf16 convert of Q/K/V activations (4096 each)
//   blocks [12288,14336): mask fp32 -> ushort and-mask (0xFFFF keep / 0 drop)
//   blocks [14336,18432): weight transpose W[k][n] fp32 -> Wt[n][k] bf16 (x4)
// ---------------------------------------------------------------------------
__global__ __launch_bounds__(256)
void preprocess(const float* __restrict__ Qin, const float* __restrict__ Kin,
                const float* __restrict__ Vin, const float* __restrict__ Msk,
                const float* __restrict__ Wq, const float* __restrict__ Wk,
                const float* __restrict__ Wv, const float* __restrict__ Wo,
                unsigned short* __restrict__ acts, unsigned short* __restrict__ m16,
                unsigned short* __restrict__ wts)
{
    __shared__ float t[32][33];
    const int bx = blockIdx.x, tid = threadIdx.x;
    if (bx < 12288) {            // activation convert
        const int which = bx >> 12;
        const float* src = (which == 0) ? Qin : (which == 1) ? Kin : Vin;
        unsigned short* dst = acts + ((size_t)which << 23);
        const size_t i = ((size_t)(bx & 4095) * 256 + tid) * 8;
        float4 a = *(const float4*)(src + i);
        float4 b = *(const float4*)(src + i + 4);
        uint4 p;
        p.x = pk2(a.x, a.y); p.y = pk2(a.z, a.w);
        p.z = pk2(b.x, b.y); p.w = pk2(b.z, b.w);
        *(uint4*)(dst + i) = p;
    } else if (bx < 14336) {     // mask expand: 8 floats -> 8 ushort and-words
        const size_t i = ((size_t)(bx - 12288) * 256 + tid) * 8;
        float4 a = *(const float4*)(Msk + i);
        float4 b = *(const float4*)(Msk + i + 4);
        uint4 o;
        o.x = ((a.x != 0.f) ? 0u : 0xFFFFu) | ((a.y != 0.f) ? 0u : 0xFFFF0000u);
        o.y = ((a.z != 0.f) ? 0u : 0xFFFFu) | ((a.w != 0.f) ? 0u : 0xFFFF0000u);
        o.z = ((b.x != 0.f) ? 0u : 0xFFFFu) | ((b.y != 0.f) ? 0u : 0xFFFF0000u);
        o.w = ((b.z != 0.f) ? 0u : 0xFFFFu) | ((b.w != 0.f) ? 0u : 0xFFFF0000u);
        *(uint4*)(m16 + i) = o;
    } else {                     // weight transpose
        const int idx = bx - 14336;
        const int z = idx >> 10, rem = idx & 1023;
        const float* W = (z == 0) ? Wq : (z == 1) ? Wk : (z == 2) ? Wv : Wo;
        unsigned short* Wt = wts + ((size_t)z << 20);
        const int n0 = (rem & 31) << 5, k0 = (rem >> 5) << 5;
        const int tx = tid & 31, ty = tid >> 5;  // 32 x 8
#pragma unroll
        for (int i = 0; i < 4; i++)
            t[ty + 8 * i][tx] = W[(size_t)(k0 + ty + 8 * i) * 1024 + n0 + tx];
        __syncthreads();
#pragma unroll
        for (int i = 0; i < 4; i++)
            Wt[(size_t)(n0 + ty + 8 * i) * 1024 + k0 + tx] = f2bf(t[tx][ty + 8 * i]);
    }
}

// ---------------------------------------------------------------------------
// Fused QKV projection GEMM, double-buffered global_load_lds staging.
// z = blockIdx.z selects {Q,K,V}. 4 blocks/CU residency (36KB LDS x 4 = 144KB).
// ---------------------------------------------------------------------------
__global__ __launch_bounds__(256, 4)
void qkv_gemm(const unsigned short* __restrict__ A0,
              const unsigned short* __restrict__ W0,
              const float* __restrict__ bq, const float* __restrict__ bk,
              const float* __restrict__ bv,
              unsigned short* __restrict__ out0)
{
    __shared__ __align__(16) unsigned short sm[18432];

    const int z = blockIdx.z;
    const unsigned short* A  = A0 + ((size_t)z << 23);
    const unsigned short* Wt = W0 + ((size_t)z << 20);
    const float* bias = (z == 0) ? bq : (z == 1) ? bk : bv;
    unsigned short* ob = out0 + ((size_t)z << 23);

    const int tid = threadIdx.x, lane = tid & 63, wave = tid >> 6;
    const int quad = lane >> 4, l16 = lane & 15;
    const int wr = wave >> 1, wc = wave & 1;
    const int m0 = blockIdx.x * 128, n0 = blockIdx.y * 128;

    const char* Ab = (const char*)A  + (size_t)m0 * 2048;
    const char* Bb = (const char*)Wt + (size_t)n0 * 2048;
    const int sr0 = tid >> 2, sc0 = (tid & 3) << 4;

    f32x4 acc[4][4];
#pragma unroll
    for (int i = 0; i < 4; i++)
#pragma unroll
        for (int j = 0; j < 4; j++) acc[i][j] = (f32x4){0.f, 0.f, 0.f, 0.f};

    {
        char* Ad = (char*)sm;
        char* Bd = Ad + 8192;
        ld16_lds(Ab + (size_t)sr0 * 2048 + sc0,        Ad + tid * 16);
        ld16_lds(Ab + (size_t)(sr0 + 64) * 2048 + sc0, Ad + (256 + tid) * 16);
        ld16_lds(Bb + (size_t)sr0 * 2048 + sc0,        Bd + tid * 16);
        ld16_lds(Bb + (size_t)(sr0 + 64) * 2048 + sc0, Bd + (256 + tid) * 16);
    }

    for (int it = 0; it < 32; ++it) {
        const int cur = it & 1;
        __syncthreads();  // vmcnt drained: buf[cur] staged; buf[cur^1] readers done
        if (it < 31) {
            const int kb2 = (it + 1) * 64;
            char* Ad = (char*)(sm + (cur ^ 1) * 8192);
            char* Bd = Ad + 8192;
            ld16_lds(Ab + (size_t)sr0 * 2048 + kb2 + sc0,        Ad + tid * 16);
            ld16_lds(Ab + (size_t)(sr0 + 64) * 2048 + kb2 + sc0, Ad + (256 + tid) * 16);
            ld16_lds(Bb + (size_t)sr0 * 2048 + kb2 + sc0,        Bd + tid * 16);
            ld16_lds(Bb + (size_t)(sr0 + 64) * 2048 + kb2 + sc0, Bd + (256 + tid) * 16);
        }
        const unsigned short* As = sm + cur * 8192;
        const unsigned short* Bs = As + 4096;

        bf16x8 af[4], bfr[4];
#pragma unroll
        for (int mt = 0; mt < 4; mt++)
            af[mt] = *(const bf16x8*)&As[(wr * 64 + mt * 16 + l16) * 32 + quad * 8];
#pragma unroll
        for (int nt = 0; nt < 4; nt++)
            bfr[nt] = *(const bf16x8*)&Bs[(wc * 64 + nt * 16 + l16) * 32 + quad * 8];
#pragma unroll
        for (int mt = 0; mt < 4; mt++)
#pragma unroll
            for (int nt = 0; nt < 4; nt++)
                acc[mt][nt] = __builtin_amdgcn_mfma_f32_16x16x32_bf16(af[mt], bfr[nt], acc[mt][nt], 0, 0, 0);
    }

    float bvv[4];
#pragma unroll
    for (int nt = 0; nt < 4; nt++) bvv[nt] = bias[n0 + wc * 64 + nt * 16 + l16];

    if (z < 2) {
        // LDS bounce: [128][132] 2B tile, then coalesced uint4 stores.
        __syncthreads();  // all waves done reading sm (last K-tile)
        unsigned short* T = sm;
#pragma unroll
        for (int mt = 0; mt < 4; mt++) {
            const int row = wr * 64 + mt * 16 + quad * 4;
#pragma unroll
            for (int nt = 0; nt < 4; nt++) {
                const int col = wc * 64 + nt * 16 + l16;
#pragma unroll
                for (int r = 0; r < 4; r++) {
                    float o = acc[mt][nt][r] + bvv[nt];
                    if (z == 0) o *= QSCALE;
                    T[(row + r) * 132 + col] = f2bf(o);
                }
            }
        }
        __syncthreads();
#pragma unroll
        for (int j = 0; j < 8; j++) {
            const int id = j * 256 + tid;
            const int row = id >> 4, cc = id & 15;      // 16 x 8-elem chunks per row
            const uint2 v01 = *(const uint2*)&T[row * 132 + cc * 8];
            const uint2 v23 = *(const uint2*)&T[row * 132 + cc * 8 + 4];
            uint4 v; v.x = v01.x; v.y = v01.y; v.z = v23.x; v.w = v23.y;
            const int mg = m0 + row;
            const int b = mg >> 11, s = mg & 2047;
            const int ng = n0 + cc * 8;
            const int h = ng >> 6, dk = ng & 63;
            *(uint4*)&ob[((size_t)((b << 4) + h) * 2048 + s) * 64 + dk] = v;
        }
    } else {  // z==2: V transposed [B,H,DV,S] via LDS transpose (16B stores)
        __syncthreads();
        unsigned short* T = sm + wave * (64 * 72);
#pragma unroll
        for (int mt = 0; mt < 4; mt++)
#pragma unroll
            for (int nt = 0; nt < 4; nt++)
#pragma unroll
                for (int r = 0; r < 4; r++)
                    T[(nt * 16 + l16) * 72 + mt * 16 + quad * 4 + r] = f2bf(acc[mt][nt][r] + bvv[nt]);
        __syncthreads();
#pragma unroll
        for (int i = 0; i < 8; i++) {
            const int nl = i * 8 + (lane >> 3);
            const int mc = lane & 7;
            uint4 v = *(const uint4*)&T[nl * 72 + mc * 8];
            const int n  = n0 + wc * 64 + nl;
            const int mg = m0 + wr * 64 + mc * 8;
            const int b = mg >> 11, s = mg & 2047;
            const int h = n >> 6, dv = n & 63;
            *(uint4*)&ob[((size_t)((b << 4) + h) * 64 + dv) * 2048 + s] = v;
        }
    }
}

// ---------------------------------------------------------------------------
// Final projection GEMM (ctx bf16 @ Wo^T + bo -> fp32), dbuf structure.
// ---------------------------------------------------------------------------
__global__ __launch_bounds__(256, 3)
void gemm_final(const unsigned short* __restrict__ A,
                const unsigned short* __restrict__ Wt, const float* __restrict__ bias,
                float* __restrict__ of)
{
    __shared__ __align__(16) unsigned short sm[16384];

    const int tid = threadIdx.x, lane = tid & 63, wave = tid >> 6;
    const int quad = lane >> 4, l16 = lane & 15;
    const int wr = wave >> 1, wc = wave & 1;
    const int m0 = blockIdx.x * 128, n0 = blockIdx.y * 128;

    const char* Ab = (const char*)A  + (size_t)m0 * 2048;
    const char* Bb = (const char*)Wt + (size_t)n0 * 2048;
    const int sr0 = tid >> 2, sc0 = (tid & 3) << 4;

    f32x4 acc[4][4];
#pragma unroll
    for (int i = 0; i < 4; i++)
#pragma unroll
        for (int j = 0; j < 4; j++) acc[i][j] = (f32x4){0.f, 0.f, 0.f, 0.f};

    {
        char* Ad = (char*)sm;
        char* Bd = Ad + 8192;
        ld16_lds(Ab + (size_t)sr0 * 2048 + sc0,        Ad + tid * 16);
        ld16_lds(Ab + (size_t)(sr0 + 64) * 2048 + sc0, Ad + (256 + tid) * 16);
        ld16_lds(Bb + (size_t)sr0 * 2048 + sc0,        Bd + tid * 16);
        ld16_lds(Bb + (size_t)(sr0 + 64) * 2048 + sc0, Bd + (256 + tid) * 16);
    }

    for (int it = 0; it < 32; ++it) {
        const int cur = it & 1;
        __syncthreads();
        if (it < 31) {
            const int kb2 = (it + 1) * 64;
            char* Ad = (char*)(sm + (cur ^ 1) * 8192);
            char* Bd = Ad + 8192;
            ld16_lds(Ab + (size_t)sr0 * 2048 + kb2 + sc0,        Ad + tid * 16);
            ld16_lds(Ab + (size_t)(sr0 + 64) * 2048 + kb2 + sc0, Ad + (256 + tid) * 16);
            ld16_lds(Bb + (size_t)sr0 * 2048 + kb2 + sc0,        Bd + tid * 16);
            ld16_lds(Bb + (size_t)(sr0 + 64) * 2048 + kb2 + sc0, Bd + (256 + tid) * 16);
        }
        const unsigned short* As = sm + cur * 8192;
        const unsigned short* Bs = As + 4096;

        bf16x8 af[4], bfr[4];
#pragma unroll
        for (int mt = 0; mt < 4; mt++)
            af[mt] = *(const bf16x8*)&As[(wr * 64 + mt * 16 + l16) * 32 + quad * 8];
#pragma unroll
        for (int nt = 0; nt < 4; nt++)
            bfr[nt] = *(const bf16x8*)&Bs[(wc * 64 + nt * 16 + l16) * 32 + quad * 8];
#pragma unroll
        for (int mt = 0; mt < 4; mt++)
#pragma unroll
            for (int nt = 0; nt < 4; nt++)
                acc[mt][nt] = __builtin_amdgcn_mfma_f32_16x16x32_bf16(af[mt], bfr[nt], acc[mt][nt], 0, 0, 0);
    }

    float bvv[4];
#pragma unroll
    for (int nt = 0; nt < 4; nt++) bvv[nt] = bias[n0 + wc * 64 + nt * 16 + l16];
#pragma unroll
    for (int mt = 0; mt < 4; mt++) {
        const int m = m0 + wr * 64 + mt * 16 + quad * 4;
#pragma unroll
        for (int nt = 0; nt < 4; nt++) {
            const int n = n0 + wc * 64 + nt * 16 + l16;
#pragma unroll
            for (int r = 0; r < 4; r++)
                of[(size_t)(m + r) * 1024 + n] = acc[mt][nt][r] + bvv[nt];
        }
    }
}

// ---------------------------------------------------------------------------
// Flash attention R12: R8 structure + and-word masking (R11) + R8's
// one-iteration-ahead mask prefetch restored.
// R11 post-mortem: same-iter mask gather (16 rows x 4KB-strided lines) put
// ~200-900cy L2/L3 latency on the serial chain each iter (VALUBusy 52->23
// but dur 133->199). Fix: load t+1's mask words at body top (after staging
// issues), consume prev regs in SM. Carried state +24-32 VGPR; tripwire:
// WRITE_SIZE > 30MB means spill -> revert.
// ---------------------------------------------------------------------------
__global__ __launch_bounds__(256, 4)
void attn_kernel(const unsigned short* __restrict__ q,
                 const unsigned short* __restrict__ k,
                 const unsigned short* __restrict__ vT,
                 const unsigned short* __restrict__ m16,
                 unsigned short* __restrict__ ctx)
{
    __shared__ __align__(16) unsigned short Ks[2][64 * 64];  // 16 KB
    __shared__ __align__(16) unsigned short Vs[2][64 * 64];  // 16 KB

    const int tid = threadIdx.x, lane = tid & 63, wave = tid >> 6;
    const int quad = lane >> 4, l16 = lane & 15;
    const int sw = l16 & 7;
    const int bid = blockIdx.x;
    const int qblk = bid & 15, h = (bid >> 4) & 15, b = bid >> 8;

    const unsigned short* qb = q  + (size_t)(b * 16 + h) * 2048 * 64;
    const unsigned short* kb = k  + (size_t)(b * 16 + h) * 2048 * 64;
    const unsigned short* vb = vT + (size_t)(b * 16 + h) * 64 * 2048;

    const int c0 = tid, c1 = 256 + tid;
    const int r0 = c0 >> 3, gcc0 = (c0 & 7) ^ (r0 & 7);
    const int r1 = c1 >> 3, gcc1 = (c1 & 7) ^ (r1 & 7);

    int qrow[2];
    bf16x8 qf[2][2];
    f32x4 O0[4], O1[4];
    f32x4 lacc0 = (f32x4){0.f,0.f,0.f,0.f}, lacc1 = (f32x4){0.f,0.f,0.f,0.f};
    const bf16x4 vones = (bf16x4){(short)0x3F80, (short)0x3F80, (short)0x3F80, (short)0x3F80};
#pragma unroll
    for (int g = 0; g < 2; g++) {
        qrow[g] = qblk * 128 + wave * 32 + g * 16 + l16;
        qf[g][0] = *(const bf16x8*)&qb[qrow[g] * 64 + quad * 8];
        qf[g][1] = *(const bf16x8*)&qb[qrow[g] * 64 + 32 + quad * 8];
    }
#pragma unroll
    for (int i = 0; i < 4; i++) { O0[i] = (f32x4){0.f,0.f,0.f,0.f}; O1[i] = (f32x4){0.f,0.f,0.f,0.f}; }
    // per-lane mask row base + quad column offset (16-bit words)
    const unsigned short* mr0 = m16 + (size_t)qrow[0] * 2048 + quad * 4;
    const unsigned short* mr1 = m16 + (size_t)qrow[1] * 2048 + quad * 4;

    {
        ld16_lds((const char*)kb + (size_t)r0 * 128 + gcc0 * 16, (char*)Ks[0] + c0 * 16);
        ld16_lds((const char*)kb + (size_t)r1 * 128 + gcc1 * 16, (char*)Ks[0] + c1 * 16);
        ld16_lds((const char*)vb + (size_t)r0 * 4096 + gcc0 * 16, (char*)Vs[0] + c0 * 16);
        ld16_lds((const char*)vb + (size_t)r1 * 4096 + gcc1 * 16, (char*)Vs[0] + c1 * 16);
    }
    // mask words for iter 0 (consumed in body 0's SM phase)
    uint2 mwc0[4], mwc1[4];
#pragma unroll
    for (int mt = 0; mt < 4; mt++) {
        mwc0[mt] = *(const uint2*)&mr0[mt * 16];
        mwc1[mt] = *(const uint2*)&mr1[mt * 16];
    }

    for (int it = 0; it < 32; ++it) {
        const int kt = it << 6;
        const int cur = it & 1, nxt = cur ^ 1;
        __syncthreads();

        if (it < 31) {
            const char* kg = (const char*)kb + (size_t)(kt + 64) * 128;
            const char* vg = (const char*)vb + (size_t)(kt + 64) * 2;
            ld16_lds(kg + (size_t)r0 * 128 + gcc0 * 16, (char*)Ks[nxt] + c0 * 16);
            ld16_lds(kg + (size_t)r1 * 128 + gcc1 * 16, (char*)Ks[nxt] + c1 * 16);
            ld16_lds(vg + (size_t)r0 * 4096 + gcc0 * 16, (char*)Vs[nxt] + c0 * 16);
            ld16_lds(vg + (size_t)r1 * 4096 + gcc1 * 16, (char*)Vs[nxt] + c1 * 16);
        }
        // prefetch next iter's mask words (consumed next body; ~full iter to cover)
        const int mkt = (it < 31) ? kt + 64 : 0;
        uint2 mwn0[4], mwn1[4];
#pragma unroll
        for (int mt = 0; mt < 4; mt++) {
            mwn0[mt] = *(const uint2*)&mr0[mkt + mt * 16];
            mwn1[mt] = *(const uint2*)&mr1[mkt + mt * 16];
        }

        const unsigned short* Kc = Ks[cur];
        const unsigned short* Vc = Vs[cur];

        // ---- S^T = K . Q^T for both groups ----
        f32x4 S0[4], S1[4];
        __builtin_amdgcn_s_setprio(1);
#pragma unroll
        for (int mt = 0; mt < 4; mt++) {
            const unsigned short* kp = Kc + (mt * 16 + l16) * 64;
            bf16x8 ka0 = *(const bf16x8*)&kp[((quad    ) ^ sw) * 8];
            bf16x8 ka1 = *(const bf16x8*)&kp[((4 + quad) ^ sw) * 8];
            f32x4 z0 = (f32x4){0.f,0.f,0.f,0.f};
            f32x4 z1 = (f32x4){0.f,0.f,0.f,0.f};
            z0 = __builtin_amdgcn_mfma_f32_16x16x32_bf16(ka0, qf[0][0], z0, 0, 0, 0);
            S0[mt] = __builtin_amdgcn_mfma_f32_16x16x32_bf16(ka1, qf[0][1], z0, 0, 0, 0);
            z1 = __builtin_amdgcn_mfma_f32_16x16x32_bf16(ka0, qf[1][0], z1, 0, 0, 0);
            S1[mt] = __builtin_amdgcn_mfma_f32_16x16x32_bf16(ka1, qf[1][1], z1, 0, 0, 0);
        }
        __builtin_amdgcn_s_setprio(0);
        // ---- exp2 + pack + and-mask (mask regs loaded last iter: no wait) ----
        bf16x4 pf0[4], pf1[4];
#pragma unroll
        for (int mt = 0; mt < 4; mt++) {
            float p0[4], p1[4];
#pragma unroll
            for (int r = 0; r < 4; r++) {
                p0[r] = __builtin_amdgcn_exp2f(S0[mt][r]);
                p1[r] = __builtin_amdgcn_exp2f(S1[mt][r]);
            }
            uint2 u0, u1;
            u0.x = pkpair(p0[0], p0[1]) & mwc0[mt].x;
            u0.y = pkpair(p0[2], p0[3]) & mwc0[mt].y;
            u1.x = pkpair(p1[0], p1[1]) & mwc1[mt].x;
            u1.y = pkpair(p1[2], p1[3]) & mwc1[mt].y;
            pf0[mt] = __builtin_bit_cast(bf16x4, u0);
            pf1[mt] = __builtin_bit_cast(bf16x4, u1);
        }
        // ---- l += ones . P^T  (MFMA pipe; all rows hold the column sum) ----
        __builtin_amdgcn_s_setprio(1);
#pragma unroll
        for (int mt = 0; mt < 4; mt++) {
            lacc0 = __builtin_amdgcn_mfma_f32_16x16x16bf16_1k(vones, pf0[mt], lacc0, 0, 0, 0);
            lacc1 = __builtin_amdgcn_mfma_f32_16x16x16bf16_1k(vones, pf1[mt], lacc1, 0, 0, 0);
        }
        // ---- O^T += V^T . P^T ----
#pragma unroll
        for (int dvt = 0; dvt < 4; dvt++) {
            const unsigned short* vp = Vc + (dvt * 16 + l16) * 64;
#pragma unroll
            for (int mt = 0; mt < 4; mt++) {
                uint2 vv = *(const uint2*)&vp[((2 * mt + (quad >> 1)) ^ sw) * 8 + (quad & 1) * 4];
                bf16x4 va = __builtin_bit_cast(bf16x4, vv);
                O0[dvt] = __builtin_amdgcn_mfma_f32_16x16x16bf16_1k(va, pf0[mt], O0[dvt], 0, 0, 0);
                O1[dvt] = __builtin_amdgcn_mfma_f32_16x16x16bf16_1k(va, pf1[mt], O1[dvt], 0, 0, 0);
            }
        }
        __builtin_amdgcn_s_setprio(0);
#pragma unroll
        for (int mt = 0; mt < 4; mt++) {
            mwc0[mt] = mwn0[mt]; mwc1[mt] = mwn1[mt];
        }
    }
    // ---- epilogue: every lane already holds l(q=l16) in lacc (rows equal) ----
#pragma unroll
    for (int g = 0; g < 2; g++) {
        const float rl = __builtin_amdgcn_rcpf(g ? lacc1[0] : lacc0[0]);
        const f32x4* O = g ? O1 : O0;
#pragma unroll
        for (int dvt = 0; dvt < 4; dvt++) {
            uint2 st;
            st.x = pk2(O[dvt][0] * rl, O[dvt][1] * rl);
            st.y = pk2(O[dvt][2] * rl, O[dvt][3] * rl);
            *(uint2*)&ctx[(size_t)(b * 2048 + qrow[g]) * 1024 + h * 64 + dvt * 16 + quad * 4] = st;
        }
    }
}

// ---------------------------------------------------------------------------
extern "C" void kernel_launch(void* const* d_in, const int* in_sizes, int n_in,
                              void* d_out, int out_size, void* d_ws, size_t ws_size,
                              hipStream_t stream)
{
    const float* Qin = (const float*)d_in[0];
    const float* Kin = (const float*)d_in[1];
    const float* Vin = (const float*)d_in[2];
    const float* Msk = (const float*)d_in[3];
    const float* Wq  = (const float*)d_in[4];
    const float* bq  = (const float*)d_in[5];
    const float* Wk  = (const float*)d_in[6];
    const float* bk  = (const float*)d_in[7];
    const float* Wv  = (const float*)d_in[8];
    const float* bv  = (const float*)d_in[9];
    const float* Wo  = (const float*)d_in[10];
    const float* bo  = (const float*)d_in[11];

    unsigned short* w = (unsigned short*)d_ws;
    unsigned short* wts  = w;                       // 4 x 1M elems (bf16 weights^T)
    unsigned short* wto  = w + 3u * (1u << 20);
    unsigned short* qcv  = w + 4u * (1u << 20);     // bf16 activations, 3 x 8M
    unsigned short* qb   = qcv + 3u * (1u << 23);   // projections, 3 x 8M
    unsigned short* kb   = qb  + (1u << 23);
    unsigned short* vTb  = kb  + (1u << 23);
    unsigned short* ctxb = qcv;                     // alias: qcv dead after qkv_gemm
    unsigned short* m16  = vTb + (1u << 23);        // 4M ushorts = 8 MB and-mask
    // total ws use: 8 MB + 96 MB + 8 MB = 112 MB

    preprocess<<<18432, 256, 0, stream>>>(Qin, Kin, Vin, Msk, Wq, Wk, Wv, Wo,
                                          qcv, m16, wts);
    qkv_gemm<<<dim3(64, 8, 3), 256, 0, stream>>>(qcv, wts, bq, bk, bv, qb);
    attn_kernel<<<1024, 256, 0, stream>>>(qb, kb, vTb, m16, ctxb);
    gemm_final<<<dim3(64, 8), 256, 0, stream>>>(ctxb, wto, bo, (float*)d_out);
}

// Round 8
// 375.574 us; speedup vs baseline: 1.5081x; 1.5081x over previous
//
#include <hip/hip_runtime.h>
#include <cstdint>
#include <cstddef>

typedef __attribute__((ext_vector_type(8))) short bf16x8;
typedef __attribute__((ext_vector_type(4))) short bf16x4;
typedef __attribute__((ext_vector_type(4))) float f32x4;

__device__ __forceinline__ unsigned short f2bf(float f) {
    union { float f; unsigned int u; } v; v.f = f;
    unsigned int r = v.u + 0x7FFFu + ((v.u >> 16) & 1u);
    return (unsigned short)(r >> 16);
}
__device__ __forceinline__ unsigned int pk2(float a, float b) {
    return (unsigned int)f2bf(a) | ((unsigned int)f2bf(b) << 16);
}
// pack two f32 -> bf16x2 in one VALU op when the HW builtin exists
__device__ __forceinline__ unsigned int pkpair(float a, float b) {
#if __has_builtin(__builtin_amdgcn_cvt_pk_bf16_f32)
    auto r = __builtin_amdgcn_cvt_pk_bf16_f32(a, b);
    return __builtin_bit_cast(unsigned int, r);
#else
    unsigned int ua = __builtin_bit_cast(unsigned int, a) + 0x8000u;
    unsigned int ub = __builtin_bit_cast(unsigned int, b) + 0x8000u;
    return __builtin_amdgcn_perm(ub, ua, 0x07060302u);  // [a_hi16 | b_hi16<<16]
#endif
}

// async global->LDS, 16B per lane (global_load_lds_dwordx4).
// LDS dest semantics: wave-uniform base + lane*16 (m104/m108).
typedef __attribute__((address_space(1))) void gvoid;
typedef __attribute__((address_space(3))) void svoid;
__device__ __forceinline__ void ld16_lds(const void* g, void* l) {
    __builtin_amdgcn_global_load_lds((gvoid*)g, (svoid*)l, 16, 0, 0);
}

#define QSCALE 0.1803368801111204f  // 0.125 * log2(e): folded into Q so scores feed exp2

// ---------------------------------------------------------------------------
// Merged preprocessing:
//   blocks [0,12288):    fp32->bf16 convert of Q/K/V activations (4096 each)
//   blocks [12288,14336): mask fp32 -> TILED and-word table (R13):
//       mwt[((kt*4+quad)*2048 + row)*16 + mt*4 + r] = (masked? 0 : 0xFFFF)
//       for key = kt*64 + mt*16 + quad*4 + r. Each attn lane's per-iter mask
//       is 32B CONTIGUOUS (2 x uint4) instead of 16 lines 4KB apart (R11 bug).
//   blocks [14336,18432): weight transpose W[k][n] fp32 -> Wt[n][k] bf16 (x4)
// ---------------------------------------------------------------------------
__global__ __launch_bounds__(256)
void preprocess(const float* __restrict__ Qin, const float* __restrict__ Kin,
                const float* __restrict__ Vin, const float* __restrict__ Msk,
                const float* __restrict__ Wq, const float* __restrict__ Wk,
                const float* __restrict__ Wv, const float* __restrict__ Wo,
                unsigned short* __restrict__ acts, unsigned short* __restrict__ m16,
                unsigned short* __restrict__ wts)
{
    __shared__ float t[32][33];
    const int bx = blockIdx.x, tid = threadIdx.x;
    if (bx < 12288) {            // activation convert
        const int which = bx >> 12;
        const float* src = (which == 0) ? Qin : (which == 1) ? Kin : Vin;
        unsigned short* dst = acts + ((size_t)which << 23);
        const size_t i = ((size_t)(bx & 4095) * 256 + tid) * 8;
        float4 a = *(const float4*)(src + i);
        float4 b = *(const float4*)(src + i + 4);
        uint4 p;
        p.x = pk2(a.x, a.y); p.y = pk2(a.z, a.w);
        p.z = pk2(b.x, b.y); p.w = pk2(b.z, b.w);
        *(uint4*)(dst + i) = p;
    } else if (bx < 14336) {     // mask expand -> tiled and-words
        const int row = bx - 12288;          // one row per block (2048 rows)
        const int k0 = tid * 8;              // 8 consecutive keys per thread
        const float* src = Msk + (size_t)row * 2048 + k0;
        float4 a = *(const float4*)src;
        float4 b = *(const float4*)(src + 4);
        unsigned int m0 = (a.x != 0.f) ? 0u : 0xFFFFu;
        unsigned int m1 = (a.y != 0.f) ? 0u : 0xFFFFu;
        unsigned int m2 = (a.z != 0.f) ? 0u : 0xFFFFu;
        unsigned int m3 = (a.w != 0.f) ? 0u : 0xFFFFu;
        unsigned int m4 = (b.x != 0.f) ? 0u : 0xFFFFu;
        unsigned int m5 = (b.y != 0.f) ? 0u : 0xFFFFu;
        unsigned int m6 = (b.z != 0.f) ? 0u : 0xFFFFu;
        unsigned int m7 = (b.w != 0.f) ? 0u : 0xFFFFu;
        const int kt = k0 >> 6, mt = (k0 >> 4) & 3, q0 = (k0 >> 2) & 3;  // q0 even
        uint2 A; A.x = m0 | (m1 << 16); A.y = m2 | (m3 << 16);
        uint2 B; B.x = m4 | (m5 << 16); B.y = m6 | (m7 << 16);
        const size_t baseA = ((size_t)(kt * 4 + q0    ) * 2048 + row) * 16 + mt * 4;
        const size_t baseB = ((size_t)(kt * 4 + q0 + 1) * 2048 + row) * 16 + mt * 4;
        *(uint2*)(m16 + baseA) = A;
        *(uint2*)(m16 + baseB) = B;
    } else {                     // weight transpose
        const int idx = bx - 14336;
        const int z = idx >> 10, rem = idx & 1023;
        const float* W = (z == 0) ? Wq : (z == 1) ? Wk : (z == 2) ? Wv : Wo;
        unsigned short* Wt = wts + ((size_t)z << 20);
        const int n0 = (rem & 31) << 5, k0 = (rem >> 5) << 5;
        const int tx = tid & 31, ty = tid >> 5;  // 32 x 8
#pragma unroll
        for (int i = 0; i < 4; i++)
            t[ty + 8 * i][tx] = W[(size_t)(k0 + ty + 8 * i) * 1024 + n0 + tx];
        __syncthreads();
#pragma unroll
        for (int i = 0; i < 4; i++)
            Wt[(size_t)(n0 + ty + 8 * i) * 1024 + k0 + tx] = f2bf(t[tx][ty + 8 * i]);
    }
}

// ---------------------------------------------------------------------------
// Fused QKV projection GEMM, double-buffered global_load_lds staging.
// z = blockIdx.z selects {Q,K,V}. 4 blocks/CU residency (36KB LDS x 4 = 144KB).
// ---------------------------------------------------------------------------
__global__ __launch_bounds__(256, 4)
void qkv_gemm(const unsigned short* __restrict__ A0,
              const unsigned short* __restrict__ W0,
              const float* __restrict__ bq, const float* __restrict__ bk,
              const float* __restrict__ bv,
              unsigned short* __restrict__ out0)
{
    __shared__ __align__(16) unsigned short sm[18432];

    const int z = blockIdx.z;
    const unsigned short* A  = A0 + ((size_t)z << 23);
    const unsigned short* Wt = W0 + ((size_t)z << 20);
    const float* bias = (z == 0) ? bq : (z == 1) ? bk : bv;
    unsigned short* ob = out0 + ((size_t)z << 23);

    const int tid = threadIdx.x, lane = tid & 63, wave = tid >> 6;
    const int quad = lane >> 4, l16 = lane & 15;
    const int wr = wave >> 1, wc = wave & 1;
    const int m0 = blockIdx.x * 128, n0 = blockIdx.y * 128;

    const char* Ab = (const char*)A  + (size_t)m0 * 2048;
    const char* Bb = (const char*)Wt + (size_t)n0 * 2048;
    const int sr0 = tid >> 2, sc0 = (tid & 3) << 4;

    f32x4 acc[4][4];
#pragma unroll
    for (int i = 0; i < 4; i++)
#pragma unroll
        for (int j = 0; j < 4; j++) acc[i][j] = (f32x4){0.f, 0.f, 0.f, 0.f};

    {
        char* Ad = (char*)sm;
        char* Bd = Ad + 8192;
        ld16_lds(Ab + (size_t)sr0 * 2048 + sc0,        Ad + tid * 16);
        ld16_lds(Ab + (size_t)(sr0 + 64) * 2048 + sc0, Ad + (256 + tid) * 16);
        ld16_lds(Bb + (size_t)sr0 * 2048 + sc0,        Bd + tid * 16);
        ld16_lds(Bb + (size_t)(sr0 + 64) * 2048 + sc0, Bd + (256 + tid) * 16);
    }

    for (int it = 0; it < 32; ++it) {
        const int cur = it & 1;
        __syncthreads();  // vmcnt drained: buf[cur] staged; buf[cur^1] readers done
        if (it < 31) {
            const int kb2 = (it + 1) * 64;
            char* Ad = (char*)(sm + (cur ^ 1) * 8192);
            char* Bd = Ad + 8192;
            ld16_lds(Ab + (size_t)sr0 * 2048 + kb2 + sc0,        Ad + tid * 16);
            ld16_lds(Ab + (size_t)(sr0 + 64) * 2048 + kb2 + sc0, Ad + (256 + tid) * 16);
            ld16_lds(Bb + (size_t)sr0 * 2048 + kb2 + sc0,        Bd + tid * 16);
            ld16_lds(Bb + (size_t)(sr0 + 64) * 2048 + kb2 + sc0, Bd + (256 + tid) * 16);
        }
        const unsigned short* As = sm + cur * 8192;
        const unsigned short* Bs = As + 4096;

        bf16x8 af[4], bfr[4];
#pragma unroll
        for (int mt = 0; mt < 4; mt++)
            af[mt] = *(const bf16x8*)&As[(wr * 64 + mt * 16 + l16) * 32 + quad * 8];
#pragma unroll
        for (int nt = 0; nt < 4; nt++)
            bfr[nt] = *(const bf16x8*)&Bs[(wc * 64 + nt * 16 + l16) * 32 + quad * 8];
#pragma unroll
        for (int mt = 0; mt < 4; mt++)
#pragma unroll
            for (int nt = 0; nt < 4; nt++)
                acc[mt][nt] = __builtin_amdgcn_mfma_f32_16x16x32_bf16(af[mt], bfr[nt], acc[mt][nt], 0, 0, 0);
    }

    float bvv[4];
#pragma unroll
    for (int nt = 0; nt < 4; nt++) bvv[nt] = bias[n0 + wc * 64 + nt * 16 + l16];

    if (z < 2) {
        // LDS bounce: [128][132] 2B tile, then coalesced uint4 stores.
        __syncthreads();  // all waves done reading sm (last K-tile)
        unsigned short* T = sm;
#pragma unroll
        for (int mt = 0; mt < 4; mt++) {
            const int row = wr * 64 + mt * 16 + quad * 4;
#pragma unroll
            for (int nt = 0; nt < 4; nt++) {
                const int col = wc * 64 + nt * 16 + l16;
#pragma unroll
                for (int r = 0; r < 4; r++) {
                    float o = acc[mt][nt][r] + bvv[nt];
                    if (z == 0) o *= QSCALE;
                    T[(row + r) * 132 + col] = f2bf(o);
                }
            }
        }
        __syncthreads();
#pragma unroll
        for (int j = 0; j < 8; j++) {
            const int id = j * 256 + tid;
            const int row = id >> 4, cc = id & 15;      // 16 x 8-elem chunks per row
            const uint2 v01 = *(const uint2*)&T[row * 132 + cc * 8];
            const uint2 v23 = *(const uint2*)&T[row * 132 + cc * 8 + 4];
            uint4 v; v.x = v01.x; v.y = v01.y; v.z = v23.x; v.w = v23.y;
            const int mg = m0 + row;
            const int b = mg >> 11, s = mg & 2047;
            const int ng = n0 + cc * 8;
            const int h = ng >> 6, dk = ng & 63;
            *(uint4*)&ob[((size_t)((b << 4) + h) * 2048 + s) * 64 + dk] = v;
        }
    } else {  // z==2: V transposed [B,H,DV,S] via LDS transpose (16B stores)
        __syncthreads();
        unsigned short* T = sm + wave * (64 * 72);
#pragma unroll
        for (int mt = 0; mt < 4; mt++)
#pragma unroll
            for (int nt = 0; nt < 4; nt++)
#pragma unroll
                for (int r = 0; r < 4; r++)
                    T[(nt * 16 + l16) * 72 + mt * 16 + quad * 4 + r] = f2bf(acc[mt][nt][r] + bvv[nt]);
        __syncthreads();
#pragma unroll
        for (int i = 0; i < 8; i++) {
            const int nl = i * 8 + (lane >> 3);
            const int mc = lane & 7;
            uint4 v = *(const uint4*)&T[nl * 72 + mc * 8];
            const int n  = n0 + wc * 64 + nl;
            const int mg = m0 + wr * 64 + mc * 8;
            const int b = mg >> 11, s = mg & 2047;
            const int h = n >> 6, dv = n & 63;
            *(uint4*)&ob[((size_t)((b << 4) + h) * 64 + dv) * 2048 + s] = v;
        }
    }
}

// ---------------------------------------------------------------------------
// Final projection GEMM (ctx bf16 @ Wo^T + bo -> fp32), dbuf structure.
// ---------------------------------------------------------------------------
__global__ __launch_bounds__(256, 3)
void gemm_final(const unsigned short* __restrict__ A,
                const unsigned short* __restrict__ Wt, const float* __restrict__ bias,
                float* __restrict__ of)
{
    __shared__ __align__(16) unsigned short sm[16384];

    const int tid = threadIdx.x, lane = tid & 63, wave = tid >> 6;
    const int quad = lane >> 4, l16 = lane & 15;
    const int wr = wave >> 1, wc = wave & 1;
    const int m0 = blockIdx.x * 128, n0 = blockIdx.y * 128;

    const char* Ab = (const char*)A  + (size_t)m0 * 2048;
    const char* Bb = (const char*)Wt + (size_t)n0 * 2048;
    const int sr0 = tid >> 2, sc0 = (tid & 3) << 4;

    f32x4 acc[4][4];
#pragma unroll
    for (int i = 0; i < 4; i++)
#pragma unroll
        for (int j = 0; j < 4; j++) acc[i][j] = (f32x4){0.f, 0.f, 0.f, 0.f};

    {
        char* Ad = (char*)sm;
        char* Bd = Ad + 8192;
        ld16_lds(Ab + (size_t)sr0 * 2048 + sc0,        Ad + tid * 16);
        ld16_lds(Ab + (size_t)(sr0 + 64) * 2048 + sc0, Ad + (256 + tid) * 16);
        ld16_lds(Bb + (size_t)sr0 * 2048 + sc0,        Bd + tid * 16);
        ld16_lds(Bb + (size_t)(sr0 + 64) * 2048 + sc0, Bd + (256 + tid) * 16);
    }

    for (int it = 0; it < 32; ++it) {
        const int cur = it & 1;
        __syncthreads();
        if (it < 31) {
            const int kb2 = (it + 1) * 64;
            char* Ad = (char*)(sm + (cur ^ 1) * 8192);
            char* Bd = Ad + 8192;
            ld16_lds(Ab + (size_t)sr0 * 2048 + kb2 + sc0,        Ad + tid * 16);
            ld16_lds(Ab + (size_t)(sr0 + 64) * 2048 + kb2 + sc0, Ad + (256 + tid) * 16);
            ld16_lds(Bb + (size_t)sr0 * 2048 + kb2 + sc0,        Bd + tid * 16);
            ld16_lds(Bb + (size_t)(sr0 + 64) * 2048 + kb2 + sc0, Bd + (256 + tid) * 16);
        }
        const unsigned short* As = sm + cur * 8192;
        const unsigned short* Bs = As + 4096;

        bf16x8 af[4], bfr[4];
#pragma unroll
        for (int mt = 0; mt < 4; mt++)
            af[mt] = *(const bf16x8*)&As[(wr * 64 + mt * 16 + l16) * 32 + quad * 8];
#pragma unroll
        for (int nt = 0; nt < 4; nt++)
            bfr[nt] = *(const bf16x8*)&Bs[(wc * 64 + nt * 16 + l16) * 32 + quad * 8];
#pragma unroll
        for (int mt = 0; mt < 4; mt++)
#pragma unroll
            for (int nt = 0; nt < 4; nt++)
                acc[mt][nt] = __builtin_amdgcn_mfma_f32_16x16x32_bf16(af[mt], bfr[nt], acc[mt][nt], 0, 0, 0);
    }

    float bvv[4];
#pragma unroll
    for (int nt = 0; nt < 4; nt++) bvv[nt] = bias[n0 + wc * 64 + nt * 16 + l16];
#pragma unroll
    for (int mt = 0; mt < 4; mt++) {
        const int m = m0 + wr * 64 + mt * 16 + quad * 4;
#pragma unroll
        for (int nt = 0; nt < 4; nt++) {
            const int n = n0 + wc * 64 + nt * 16 + l16;
#pragma unroll
            for (int r = 0; r < 4; r++)
                of[(size_t)(m + r) * 1024 + n] = acc[mt][nt][r] + bvv[nt];
        }
    }
}

// ---------------------------------------------------------------------------
// Flash attention R13: R8 structure + and-word masking via TILED mask table.
// Per iter, each lane's mask = 32B contiguous (2 x uint4), loaded right after
// the barrier (before staging -> waitcnt for mask needs vmcnt(8), not 0),
// consumed after QK (~400cy cover, table L3-resident). ZERO carried mask
// registers (R9/R12 lesson: launch_bounds(256,4) => 128-reg VGPR+AGPR cap,
// no carry headroom). SM phase per mt: 4 exp2 + 2 cvt_pk + 2 v_and.
// Masked -> 0x0000 = +0.0f, bit-identical to R8's exp2(-1e8).
// ---------------------------------------------------------------------------
__global__ __launch_bounds__(256, 4)
void attn_kernel(const unsigned short* __restrict__ q,
                 const unsigned short* __restrict__ k,
                 const unsigned short* __restrict__ vT,
                 const unsigned short* __restrict__ m16,
                 unsigned short* __restrict__ ctx)
{
    __shared__ __align__(16) unsigned short Ks[2][64 * 64];  // 16 KB
    __shared__ __align__(16) unsigned short Vs[2][64 * 64];  // 16 KB

    const int tid = threadIdx.x, lane = tid & 63, wave = tid >> 6;
    const int quad = lane >> 4, l16 = lane & 15;
    const int sw = l16 & 7;
    const int bid = blockIdx.x;
    const int qblk = bid & 15, h = (bid >> 4) & 15, b = bid >> 8;

    const unsigned short* qb = q  + (size_t)(b * 16 + h) * 2048 * 64;
    const unsigned short* kb = k  + (size_t)(b * 16 + h) * 2048 * 64;
    const unsigned short* vb = vT + (size_t)(b * 16 + h) * 64 * 2048;

    const int c0 = tid, c1 = 256 + tid;
    const int r0 = c0 >> 3, gcc0 = (c0 & 7) ^ (r0 & 7);
    const int r1 = c1 >> 3, gcc1 = (c1 & 7) ^ (r1 & 7);

    int qrow[2];
    bf16x8 qf[2][2];
    f32x4 O0[4], O1[4];
    f32x4 lacc0 = (f32x4){0.f,0.f,0.f,0.f}, lacc1 = (f32x4){0.f,0.f,0.f,0.f};
    const bf16x4 vones = (bf16x4){(short)0x3F80, (short)0x3F80, (short)0x3F80, (short)0x3F80};
#pragma unroll
    for (int g = 0; g < 2; g++) {
        qrow[g] = qblk * 128 + wave * 32 + g * 16 + l16;
        qf[g][0] = *(const bf16x8*)&qb[qrow[g] * 64 + quad * 8];
        qf[g][1] = *(const bf16x8*)&qb[qrow[g] * 64 + 32 + quad * 8];
    }
#pragma unroll
    for (int i = 0; i < 4; i++) { O0[i] = (f32x4){0.f,0.f,0.f,0.f}; O1[i] = (f32x4){0.f,0.f,0.f,0.f}; }
    // tiled mask pointers: lane's 32B row-slice for key-tile it lives at
    // m16 + ((it*4 + quad)*2048 + qrow)*16 ushorts; per-iter stride 131072.
    const unsigned short* mq0 = m16 + ((size_t)quad * 2048 + qrow[0]) * 16;
    const unsigned short* mq1 = m16 + ((size_t)quad * 2048 + qrow[1]) * 16;
    const size_t mstep = (size_t)4 * 2048 * 16;

    {
        ld16_lds((const char*)kb + (size_t)r0 * 128 + gcc0 * 16, (char*)Ks[0] + c0 * 16);
        ld16_lds((const char*)kb + (size_t)r1 * 128 + gcc1 * 16, (char*)Ks[0] + c1 * 16);
        ld16_lds((const char*)vb + (size_t)r0 * 4096 + gcc0 * 16, (char*)Vs[0] + c0 * 16);
        ld16_lds((const char*)vb + (size_t)r1 * 4096 + gcc1 * 16, (char*)Vs[0] + c1 * 16);
    }

    for (int it = 0; it < 32; ++it) {
        const int kt = it << 6;
        const int cur = it & 1, nxt = cur ^ 1;
        __syncthreads();

        // mask loads FIRST (so the pre-SM waitcnt is vmcnt(8): mask only)
        const uint4 lo0 = *(const uint4*)(mq0);
        const uint4 hi0 = *(const uint4*)(mq0 + 8);
        const uint4 lo1 = *(const uint4*)(mq1);
        const uint4 hi1 = *(const uint4*)(mq1 + 8);
        mq0 += mstep; mq1 += mstep;

        if (it < 31) {
            const char* kg = (const char*)kb + (size_t)(kt + 64) * 128;
            const char* vg = (const char*)vb + (size_t)(kt + 64) * 2;
            ld16_lds(kg + (size_t)r0 * 128 + gcc0 * 16, (char*)Ks[nxt] + c0 * 16);
            ld16_lds(kg + (size_t)r1 * 128 + gcc1 * 16, (char*)Ks[nxt] + c1 * 16);
            ld16_lds(vg + (size_t)r0 * 4096 + gcc0 * 16, (char*)Vs[nxt] + c0 * 16);
            ld16_lds(vg + (size_t)r1 * 4096 + gcc1 * 16, (char*)Vs[nxt] + c1 * 16);
        }

        const unsigned short* Kc = Ks[cur];
        const unsigned short* Vc = Vs[cur];

        // ---- S^T = K . Q^T for both groups ----
        f32x4 S0[4], S1[4];
        __builtin_amdgcn_s_setprio(1);
#pragma unroll
        for (int mt = 0; mt < 4; mt++) {
            const unsigned short* kp = Kc + (mt * 16 + l16) * 64;
            bf16x8 ka0 = *(const bf16x8*)&kp[((quad    ) ^ sw) * 8];
            bf16x8 ka1 = *(const bf16x8*)&kp[((4 + quad) ^ sw) * 8];
            f32x4 z0 = (f32x4){0.f,0.f,0.f,0.f};
            f32x4 z1 = (f32x4){0.f,0.f,0.f,0.f};
            z0 = __builtin_amdgcn_mfma_f32_16x16x32_bf16(ka0, qf[0][0], z0, 0, 0, 0);
            S0[mt] = __builtin_amdgcn_mfma_f32_16x16x32_bf16(ka1, qf[0][1], z0, 0, 0, 0);
            z1 = __builtin_amdgcn_mfma_f32_16x16x32_bf16(ka0, qf[1][0], z1, 0, 0, 0);
            S1[mt] = __builtin_amdgcn_mfma_f32_16x16x32_bf16(ka1, qf[1][1], z1, 0, 0, 0);
        }
        __builtin_amdgcn_s_setprio(0);
        // ---- exp2 + pack + and-mask ----
        bf16x4 pf0[4], pf1[4];
#pragma unroll
        for (int mt = 0; mt < 4; mt++) {
            const unsigned int ax0 = (mt == 0) ? lo0.x : (mt == 1) ? lo0.z : (mt == 2) ? hi0.x : hi0.z;
            const unsigned int ay0 = (mt == 0) ? lo0.y : (mt == 1) ? lo0.w : (mt == 2) ? hi0.y : hi0.w;
            const unsigned int ax1 = (mt == 0) ? lo1.x : (mt == 1) ? lo1.z : (mt == 2) ? hi1.x : hi1.z;
            const unsigned int ay1 = (mt == 0) ? lo1.y : (mt == 1) ? lo1.w : (mt == 2) ? hi1.y : hi1.w;
            float p0[4], p1[4];
#pragma unroll
            for (int r = 0; r < 4; r++) {
                p0[r] = __builtin_amdgcn_exp2f(S0[mt][r]);
                p1[r] = __builtin_amdgcn_exp2f(S1[mt][r]);
            }
            uint2 u0, u1;
            u0.x = pkpair(p0[0], p0[1]) & ax0;
            u0.y = pkpair(p0[2], p0[3]) & ay0;
            u1.x = pkpair(p1[0], p1[1]) & ax1;
            u1.y = pkpair(p1[2], p1[3]) & ay1;
            pf0[mt] = __builtin_bit_cast(bf16x4, u0);
            pf1[mt] = __builtin_bit_cast(bf16x4, u1);
        }
        // ---- l += ones . P^T  (MFMA pipe; all rows hold the column sum) ----
        __builtin_amdgcn_s_setprio(1);
#pragma unroll
        for (int mt = 0; mt < 4; mt++) {
            lacc0 = __builtin_amdgcn_mfma_f32_16x16x16bf16_1k(vones, pf0[mt], lacc0, 0, 0, 0);
            lacc1 = __builtin_amdgcn_mfma_f32_16x16x16bf16_1k(vones, pf1[mt], lacc1, 0, 0, 0);
        }
        // ---- O^T += V^T . P^T ----
#pragma unroll
        for (int dvt = 0; dvt < 4; dvt++) {
            const unsigned short* vp = Vc + (dvt * 16 + l16) * 64;
#pragma unroll
            for (int mt = 0; mt < 4; mt++) {
                uint2 vv = *(const uint2*)&vp[((2 * mt + (quad >> 1)) ^ sw) * 8 + (quad & 1) * 4];
                bf16x4 va = __builtin_bit_cast(bf16x4, vv);
                O0[dvt] = __builtin_amdgcn_mfma_f32_16x16x16bf16_1k(va, pf0[mt], O0[dvt], 0, 0, 0);
                O1[dvt] = __builtin_amdgcn_mfma_f32_16x16x16bf16_1k(va, pf1[mt], O1[dvt], 0, 0, 0);
            }
        }
        __builtin_amdgcn_s_setprio(0);
    }
    // ---- epilogue: every lane already holds l(q=l16) in lacc (rows equal) ----
#pragma unroll
    for (int g = 0; g < 2; g++) {
        const float rl = __builtin_amdgcn_rcpf(g ? lacc1[0] : lacc0[0]);
        const f32x4* O = g ? O1 : O0;
#pragma unroll
        for (int dvt = 0; dvt < 4; dvt++) {
            uint2 st;
            st.x = pk2(O[dvt][0] * rl, O[dvt][1] * rl);
            st.y = pk2(O[dvt][2] * rl, O[dvt][3] * rl);
            *(uint2*)&ctx[(size_t)(b * 2048 + qrow[g]) * 1024 + h * 64 + dvt * 16 + quad * 4] = st;
        }
    }
}

// ---------------------------------------------------------------------------
extern "C" void kernel_launch(void* const* d_in, const int* in_sizes, int n_in,
                              void* d_out, int out_size, void* d_ws, size_t ws_size,
                              hipStream_t stream)
{
    const float* Qin = (const float*)d_in[0];
    const float* Kin = (const float*)d_in[1];
    const float* Vin = (const float*)d_in[2];
    const float* Msk = (const float*)d_in[3];
    const float* Wq  = (const float*)d_in[4];
    const float* bq  = (const float*)d_in[5];
    const float* Wk  = (const float*)d_in[6];
    const float* bk  = (const float*)d_in[7];
    const float* Wv  = (const float*)d_in[8];
    const float* bv  = (const float*)d_in[9];
    const float* Wo  = (const float*)d_in[10];
    const float* bo  = (const float*)d_in[11];

    unsigned short* w = (unsigned short*)d_ws;
    unsigned short* wts  = w;                       // 4 x 1M elems (bf16 weights^T)
    unsigned short* wto  = w + 3u * (1u << 20);
    unsigned short* qcv  = w + 4u * (1u << 20);     // bf16 activations, 3 x 8M
    unsigned short* qb   = qcv + 3u * (1u << 23);   // projections, 3 x 8M
    unsigned short* kb   = qb  + (1u << 23);
    unsigned short* vTb  = kb  + (1u << 23);
    unsigned short* ctxb = qcv;                     // alias: qcv dead after qkv_gemm
    unsigned short* m16  = vTb + (1u << 23);        // 4M ushorts = 8 MB tiled and-mask
    // total ws use: 8 MB + 96 MB + 8 MB = 112 MB

    preprocess<<<18432, 256, 0, stream>>>(Qin, Kin, Vin, Msk, Wq, Wk, Wv, Wo,
                                          qcv, m16, wts);
    qkv_gemm<<<dim3(64, 8, 3), 256, 0, stream>>>(qcv, wts, bq, bk, bv, qb);
    attn_kernel<<<1024, 256, 0, stream>>>(qb, kb, vTb, m16, ctxb);
    gemm_final<<<dim3(64, 8), 256, 0, stream>>>(ctxb, wto, bo, (float*)d_out);
}

// Round 10
// 373.497 us; speedup vs baseline: 1.5164x; 1.0056x over previous
//
#include <hip/hip_runtime.h>
#include <cstdint>
#include <cstddef>

typedef __attribute__((ext_vector_type(8))) short bf16x8;
typedef __attribute__((ext_vector_type(4))) short bf16x4;
typedef __attribute__((ext_vector_type(4))) float f32x4;

__device__ __forceinline__ unsigned short f2bf(float f) {
    union { float f; unsigned int u; } v; v.f = f;
    unsigned int r = v.u + 0x7FFFu + ((v.u >> 16) & 1u);
    return (unsigned short)(r >> 16);
}
__device__ __forceinline__ unsigned int pk2(float a, float b) {
    return (unsigned int)f2bf(a) | ((unsigned int)f2bf(b) << 16);
}
// pack two f32 -> bf16x2 in one VALU op when the HW builtin exists
__device__ __forceinline__ unsigned int pkpair(float a, float b) {
#if __has_builtin(__builtin_amdgcn_cvt_pk_bf16_f32)
    auto r = __builtin_amdgcn_cvt_pk_bf16_f32(a, b);
    return __builtin_bit_cast(unsigned int, r);
#else
    unsigned int ua = __builtin_bit_cast(unsigned int, a) + 0x8000u;
    unsigned int ub = __builtin_bit_cast(unsigned int, b) + 0x8000u;
    return __builtin_amdgcn_perm(ub, ua, 0x07060302u);  // [a_hi16 | b_hi16<<16]
#endif
}

// async global->LDS, 16B per lane (global_load_lds_dwordx4).
// LDS dest semantics: wave-uniform base + lane*16 (m104/m108).
typedef __attribute__((address_space(1))) void gvoid;
typedef __attribute__((address_space(3))) void svoid;
__device__ __forceinline__ void ld16_lds(const void* g, void* l) {
    __builtin_amdgcn_global_load_lds((gvoid*)g, (svoid*)l, 16, 0, 0);
}

#define QSCALE 0.1803368801111204f  // 0.125 * log2(e): folded into Q so scores feed exp2

// ---------------------------------------------------------------------------
// Merged preprocessing:
//   blocks [0,12288):    fp32->bf16 convert of Q/K/V activations (4096 each)
//   blocks [12288,14336): mask fp32 -> TILED and-word table (R13)
//   blocks [14336,18432): weight transpose W[k][n] fp32 -> Wt[n][k] bf16 (x4)
// ---------------------------------------------------------------------------
__global__ __launch_bounds__(256)
void preprocess(const float* __restrict__ Qin, const float* __restrict__ Kin,
                const float* __restrict__ Vin, const float* __restrict__ Msk,
                const float* __restrict__ Wq, const float* __restrict__ Wk,
                const float* __restrict__ Wv, const float* __restrict__ Wo,
                unsigned short* __restrict__ acts, unsigned short* __restrict__ m16,
                unsigned short* __restrict__ wts)
{
    __shared__ float t[32][33];
    const int bx = blockIdx.x, tid = threadIdx.x;
    if (bx < 12288) {            // activation convert
        const int which = bx >> 12;
        const float* src = (which == 0) ? Qin : (which == 1) ? Kin : Vin;
        unsigned short* dst = acts + ((size_t)which << 23);
        const size_t i = ((size_t)(bx & 4095) * 256 + tid) * 8;
        float4 a = *(const float4*)(src + i);
        float4 b = *(const float4*)(src + i + 4);
        uint4 p;
        p.x = pk2(a.x, a.y); p.y = pk2(a.z, a.w);
        p.z = pk2(b.x, b.y); p.w = pk2(b.z, b.w);
        *(uint4*)(dst + i) = p;
    } else if (bx < 14336) {     // mask expand -> tiled and-words
        const int row = bx - 12288;          // one row per block (2048 rows)
        const int k0 = tid * 8;              // 8 consecutive keys per thread
        const float* src = Msk + (size_t)row * 2048 + k0;
        float4 a = *(const float4*)src;
        float4 b = *(const float4*)(src + 4);
        unsigned int m0 = (a.x != 0.f) ? 0u : 0xFFFFu;
        unsigned int m1 = (a.y != 0.f) ? 0u : 0xFFFFu;
        unsigned int m2 = (a.z != 0.f) ? 0u : 0xFFFFu;
        unsigned int m3 = (a.w != 0.f) ? 0u : 0xFFFFu;
        unsigned int m4 = (b.x != 0.f) ? 0u : 0xFFFFu;
        unsigned int m5 = (b.y != 0.f) ? 0u : 0xFFFFu;
        unsigned int m6 = (b.z != 0.f) ? 0u : 0xFFFFu;
        unsigned int m7 = (b.w != 0.f) ? 0u : 0xFFFFu;
        const int kt = k0 >> 6, mt = (k0 >> 4) & 3, q0 = (k0 >> 2) & 3;  // q0 even
        uint2 A; A.x = m0 | (m1 << 16); A.y = m2 | (m3 << 16);
        uint2 B; B.x = m4 | (m5 << 16); B.y = m6 | (m7 << 16);
        const size_t baseA = ((size_t)(kt * 4 + q0    ) * 2048 + row) * 16 + mt * 4;
        const size_t baseB = ((size_t)(kt * 4 + q0 + 1) * 2048 + row) * 16 + mt * 4;
        *(uint2*)(m16 + baseA) = A;
        *(uint2*)(m16 + baseB) = B;
    } else {                     // weight transpose
        const int idx = bx - 14336;
        const int z = idx >> 10, rem = idx & 1023;
        const float* W = (z == 0) ? Wq : (z == 1) ? Wk : (z == 2) ? Wv : Wo;
        unsigned short* Wt = wts + ((size_t)z << 20);
        const int n0 = (rem & 31) << 5, k0 = (rem >> 5) << 5;
        const int tx = tid & 31, ty = tid >> 5;  // 32 x 8
#pragma unroll
        for (int i = 0; i < 4; i++)
            t[ty + 8 * i][tx] = W[(size_t)(k0 + ty + 8 * i) * 1024 + n0 + tx];
        __syncthreads();
#pragma unroll
        for (int i = 0; i < 4; i++)
            Wt[(size_t)(n0 + ty + 8 * i) * 1024 + k0 + tx] = f2bf(t[tx][ty + 8 * i]);
    }
}

// ---------------------------------------------------------------------------
// Fused QKV projection GEMM — R14: 3-buffer LDS rotation, 2-tile-deep
// prefetch, counted vmcnt(8) with raw s_barriers (T4: staging loads never
// drained in the main loop; flight time 2 iters ~1200cy > HBM ~900cy).
// Old structure's __syncthreads drained vmcnt to 0 every iter with only
// ~600cy of lead -> ~300cy structural stall/iter. Fragment math, epilogues,
// grid unchanged (verified). LDS 48KB -> 3 blocks/CU.
// vmcnt ledger: prologue 8; +4 stage = 12; vmcnt(8) drains exactly tile it.
// Tail: vmcnt(4) @30, vmcnt(0) @31.
// ---------------------------------------------------------------------------
__global__ __launch_bounds__(256, 3)
void qkv_gemm(const unsigned short* __restrict__ A0,
              const unsigned short* __restrict__ W0,
              const float* __restrict__ bq, const float* __restrict__ bk,
              const float* __restrict__ bv,
              unsigned short* __restrict__ out0)
{
    __shared__ __align__(16) unsigned short sm[24576];  // 3 x 16KB buffers

    const int z = blockIdx.z;
    const unsigned short* A  = A0 + ((size_t)z << 23);
    const unsigned short* Wt = W0 + ((size_t)z << 20);
    const float* bias = (z == 0) ? bq : (z == 1) ? bk : bv;
    unsigned short* ob = out0 + ((size_t)z << 23);

    const int tid = threadIdx.x, lane = tid & 63, wave = tid >> 6;
    const int quad = lane >> 4, l16 = lane & 15;
    const int wr = wave >> 1, wc = wave & 1;
    const int m0 = blockIdx.x * 128, n0 = blockIdx.y * 128;

    const char* Ab = (const char*)A  + (size_t)m0 * 2048;
    const char* Bb = (const char*)Wt + (size_t)n0 * 2048;
    const int sr0 = tid >> 2, sc0 = (tid & 3) << 4;

    f32x4 acc[4][4];
#pragma unroll
    for (int i = 0; i < 4; i++)
#pragma unroll
        for (int j = 0; j < 4; j++) acc[i][j] = (f32x4){0.f, 0.f, 0.f, 0.f};

#define QKV_STAGE(KT, BUF)                                                       \
    {                                                                            \
        char* Ad = (char*)(sm + (BUF) * 8192);                                   \
        char* Bd = Ad + 8192;                                                    \
        const int kb2 = (KT) * 64;                                               \
        ld16_lds(Ab + (size_t)sr0 * 2048 + kb2 + sc0,        Ad + tid * 16);     \
        ld16_lds(Ab + (size_t)(sr0 + 64) * 2048 + kb2 + sc0, Ad + (256 + tid) * 16); \
        ld16_lds(Bb + (size_t)sr0 * 2048 + kb2 + sc0,        Bd + tid * 16);     \
        ld16_lds(Bb + (size_t)(sr0 + 64) * 2048 + kb2 + sc0, Bd + (256 + tid) * 16); \
    }

    // prologue: tiles 0,1 -> bufs 0,1 (8 loads in flight)
    QKV_STAGE(0, 0)
    QKV_STAGE(1, 1)

    for (int it = 0; it < 32; ++it) {
        const int cur = it % 3;
        asm volatile("" ::: "memory");
        __builtin_amdgcn_s_barrier();          // bar1: tile it-1 reads done everywhere
        if (it < 30) QKV_STAGE(it + 2, (it + 2) % 3)   // 4 loads -> 12 outstanding
        if (it < 30)       asm volatile("s_waitcnt vmcnt(8)" ::: "memory");
        else if (it == 30) asm volatile("s_waitcnt vmcnt(4)" ::: "memory");
        else               asm volatile("s_waitcnt vmcnt(0)" ::: "memory");
        __builtin_amdgcn_s_barrier();          // bar2: tile it visible to all waves
        asm volatile("" ::: "memory");

        const unsigned short* As = sm + cur * 8192;
        const unsigned short* Bs = As + 4096;

        bf16x8 af[4], bfr[4];
#pragma unroll
        for (int mt = 0; mt < 4; mt++)
            af[mt] = *(const bf16x8*)&As[(wr * 64 + mt * 16 + l16) * 32 + quad * 8];
#pragma unroll
        for (int nt = 0; nt < 4; nt++)
            bfr[nt] = *(const bf16x8*)&Bs[(wc * 64 + nt * 16 + l16) * 32 + quad * 8];
#pragma unroll
        for (int mt = 0; mt < 4; mt++)
#pragma unroll
            for (int nt = 0; nt < 4; nt++)
                acc[mt][nt] = __builtin_amdgcn_mfma_f32_16x16x32_bf16(af[mt], bfr[nt], acc[mt][nt], 0, 0, 0);
    }

    float bvv[4];
#pragma unroll
    for (int nt = 0; nt < 4; nt++) bvv[nt] = bias[n0 + wc * 64 + nt * 16 + l16];

    if (z < 2) {
        // LDS bounce: [128][132] 2B tile, then coalesced uint4 stores.
        __syncthreads();  // all waves done reading sm (last K-tile)
        unsigned short* T = sm;
#pragma unroll
        for (int mt = 0; mt < 4; mt++) {
            const int row = wr * 64 + mt * 16 + quad * 4;
#pragma unroll
            for (int nt = 0; nt < 4; nt++) {
                const int col = wc * 64 + nt * 16 + l16;
#pragma unroll
                for (int r = 0; r < 4; r++) {
                    float o = acc[mt][nt][r] + bvv[nt];
                    if (z == 0) o *= QSCALE;
                    T[(row + r) * 132 + col] = f2bf(o);
                }
            }
        }
        __syncthreads();
#pragma unroll
        for (int j = 0; j < 8; j++) {
            const int id = j * 256 + tid;
            const int row = id >> 4, cc = id & 15;      // 16 x 8-elem chunks per row
            const uint2 v01 = *(const uint2*)&T[row * 132 + cc * 8];
            const uint2 v23 = *(const uint2*)&T[row * 132 + cc * 8 + 4];
            uint4 v; v.x = v01.x; v.y = v01.y; v.z = v23.x; v.w = v23.y;
            const int mg = m0 + row;
            const int b = mg >> 11, s = mg & 2047;
            const int ng = n0 + cc * 8;
            const int h = ng >> 6, dk = ng & 63;
            *(uint4*)&ob[((size_t)((b << 4) + h) * 2048 + s) * 64 + dk] = v;
        }
    } else {  // z==2: V transposed [B,H,DV,S] via LDS transpose (16B stores)
        __syncthreads();
        unsigned short* T = sm + wave * (64 * 72);
#pragma unroll
        for (int mt = 0; mt < 4; mt++)
#pragma unroll
            for (int nt = 0; nt < 4; nt++)
#pragma unroll
                for (int r = 0; r < 4; r++)
                    T[(nt * 16 + l16) * 72 + mt * 16 + quad * 4 + r] = f2bf(acc[mt][nt][r] + bvv[nt]);
        __syncthreads();
#pragma unroll
        for (int i = 0; i < 8; i++) {
            const int nl = i * 8 + (lane >> 3);
            const int mc = lane & 7;
            uint4 v = *(const uint4*)&T[nl * 72 + mc * 8];
            const int n  = n0 + wc * 64 + nl;
            const int mg = m0 + wr * 64 + mc * 8;
            const int b = mg >> 11, s = mg & 2047;
            const int h = n >> 6, dv = n & 63;
            *(uint4*)&ob[((size_t)((b << 4) + h) * 64 + dv) * 2048 + s] = v;
        }
    }
#undef QKV_STAGE
}

// ---------------------------------------------------------------------------
// Final projection GEMM — R14: same 3-buffer counted-vmcnt K-loop as qkv.
// ---------------------------------------------------------------------------
__global__ __launch_bounds__(256, 3)
void gemm_final(const unsigned short* __restrict__ A,
                const unsigned short* __restrict__ Wt, const float* __restrict__ bias,
                float* __restrict__ of)
{
    __shared__ __align__(16) unsigned short sm[24576];  // 3 x 16KB buffers

    const int tid = threadIdx.x, lane = tid & 63, wave = tid >> 6;
    const int quad = lane >> 4, l16 = lane & 15;
    const int wr = wave >> 1, wc = wave & 1;
    const int m0 = blockIdx.x * 128, n0 = blockIdx.y * 128;

    const char* Ab = (const char*)A  + (size_t)m0 * 2048;
    const char* Bb = (const char*)Wt + (size_t)n0 * 2048;
    const int sr0 = tid >> 2, sc0 = (tid & 3) << 4;

    f32x4 acc[4][4];
#pragma unroll
    for (int i = 0; i < 4; i++)
#pragma unroll
        for (int j = 0; j < 4; j++) acc[i][j] = (f32x4){0.f, 0.f, 0.f, 0.f};

#define FIN_STAGE(KT, BUF)                                                       \
    {                                                                            \
        char* Ad = (char*)(sm + (BUF) * 8192);                                   \
        char* Bd = Ad + 8192;                                                    \
        const int kb2 = (KT) * 64;                                               \
        ld16_lds(Ab + (size_t)sr0 * 2048 + kb2 + sc0,        Ad + tid * 16);     \
        ld16_lds(Ab + (size_t)(sr0 + 64) * 2048 + kb2 + sc0, Ad + (256 + tid) * 16); \
        ld16_lds(Bb + (size_t)sr0 * 2048 + kb2 + sc0,        Bd + tid * 16);     \
        ld16_lds(Bb + (size_t)(sr0 + 64) * 2048 + kb2 + sc0, Bd + (256 + tid) * 16); \
    }

    FIN_STAGE(0, 0)
    FIN_STAGE(1, 1)

    for (int it = 0; it < 32; ++it) {
        const int cur = it % 3;
        asm volatile("" ::: "memory");
        __builtin_amdgcn_s_barrier();          // bar1
        if (it < 30) FIN_STAGE(it + 2, (it + 2) % 3)
        if (it < 30)       asm volatile("s_waitcnt vmcnt(8)" ::: "memory");
        else if (it == 30) asm volatile("s_waitcnt vmcnt(4)" ::: "memory");
        else               asm volatile("s_waitcnt vmcnt(0)" ::: "memory");
        __builtin_amdgcn_s_barrier();          // bar2
        asm volatile("" ::: "memory");

        const unsigned short* As = sm + cur * 8192;
        const unsigned short* Bs = As + 4096;

        bf16x8 af[4], bfr[4];
#pragma unroll
        for (int mt = 0; mt < 4; mt++)
            af[mt] = *(const bf16x8*)&As[(wr * 64 + mt * 16 + l16) * 32 + quad * 8];
#pragma unroll
        for (int nt = 0; nt < 4; nt++)
            bfr[nt] = *(const bf16x8*)&Bs[(wc * 64 + nt * 16 + l16) * 32 + quad * 8];
#pragma unroll
        for (int mt = 0; mt < 4; mt++)
#pragma unroll
            for (int nt = 0; nt < 4; nt++)
                acc[mt][nt] = __builtin_amdgcn_mfma_f32_16x16x32_bf16(af[mt], bfr[nt], acc[mt][nt], 0, 0, 0);
    }

    float bvv[4];
#pragma unroll
    for (int nt = 0; nt < 4; nt++) bvv[nt] = bias[n0 + wc * 64 + nt * 16 + l16];
#pragma unroll
    for (int mt = 0; mt < 4; mt++) {
        const int m = m0 + wr * 64 + mt * 16 + quad * 4;
#pragma unroll
        for (int nt = 0; nt < 4; nt++) {
            const int n = n0 + wc * 64 + nt * 16 + l16;
#pragma unroll
            for (int r = 0; r < 4; r++)
                of[(size_t)(m + r) * 1024 + n] = acc[mt][nt][r] + bvv[nt];
        }
    }
#undef FIN_STAGE
}

// ---------------------------------------------------------------------------
// Flash attention R13 (verified 121.3us): R8 structure + tiled and-word mask.
// Untouched.
// ---------------------------------------------------------------------------
__global__ __launch_bounds__(256, 4)
void attn_kernel(const unsigned short* __restrict__ q,
                 const unsigned short* __restrict__ k,
                 const unsigned short* __restrict__ vT,
                 const unsigned short* __restrict__ m16,
                 unsigned short* __restrict__ ctx)
{
    __shared__ __align__(16) unsigned short Ks[2][64 * 64];  // 16 KB
    __shared__ __align__(16) unsigned short Vs[2][64 * 64];  // 16 KB

    const int tid = threadIdx.x, lane = tid & 63, wave = tid >> 6;
    const int quad = lane >> 4, l16 = lane & 15;
    const int sw = l16 & 7;
    const int bid = blockIdx.x;
    const int qblk = bid & 15, h = (bid >> 4) & 15, b = bid >> 8;

    const unsigned short* qb = q  + (size_t)(b * 16 + h) * 2048 * 64;
    const unsigned short* kb = k  + (size_t)(b * 16 + h) * 2048 * 64;
    const unsigned short* vb = vT + (size_t)(b * 16 + h) * 64 * 2048;

    const int c0 = tid, c1 = 256 + tid;
    const int r0 = c0 >> 3, gcc0 = (c0 & 7) ^ (r0 & 7);
    const int r1 = c1 >> 3, gcc1 = (c1 & 7) ^ (r1 & 7);

    int qrow[2];
    bf16x8 qf[2][2];
    f32x4 O0[4], O1[4];
    f32x4 lacc0 = (f32x4){0.f,0.f,0.f,0.f}, lacc1 = (f32x4){0.f,0.f,0.f,0.f};
    const bf16x4 vones = (bf16x4){(short)0x3F80, (short)0x3F80, (short)0x3F80, (short)0x3F80};
#pragma unroll
    for (int g = 0; g < 2; g++) {
        qrow[g] = qblk * 128 + wave * 32 + g * 16 + l16;
        qf[g][0] = *(const bf16x8*)&qb[qrow[g] * 64 + quad * 8];
        qf[g][1] = *(const bf16x8*)&qb[qrow[g] * 64 + 32 + quad * 8];
    }
#pragma unroll
    for (int i = 0; i < 4; i++) { O0[i] = (f32x4){0.f,0.f,0.f,0.f}; O1[i] = (f32x4){0.f,0.f,0.f,0.f}; }
    // tiled mask pointers: lane's 32B row-slice for key-tile it lives at
    // m16 + ((it*4 + quad)*2048 + qrow)*16 ushorts; per-iter stride 131072.
    const unsigned short* mq0 = m16 + ((size_t)quad * 2048 + qrow[0]) * 16;
    const unsigned short* mq1 = m16 + ((size_t)quad * 2048 + qrow[1]) * 16;
    const size_t mstep = (size_t)4 * 2048 * 16;

    {
        ld16_lds((const char*)kb + (size_t)r0 * 128 + gcc0 * 16, (char*)Ks[0] + c0 * 16);
        ld16_lds((const char*)kb + (size_t)r1 * 128 + gcc1 * 16, (char*)Ks[0] + c1 * 16);
        ld16_lds((const char*)vb + (size_t)r0 * 4096 + gcc0 * 16, (char*)Vs[0] + c0 * 16);
        ld16_lds((const char*)vb + (size_t)r1 * 4096 + gcc1 * 16, (char*)Vs[0] + c1 * 16);
    }

    for (int it = 0; it < 32; ++it) {
        const int kt = it << 6;
        const int cur = it & 1, nxt = cur ^ 1;
        __syncthreads();

        // mask loads FIRST (so the pre-SM waitcnt is vmcnt(8): mask only)
        const uint4 lo0 = *(const uint4*)(mq0);
        const uint4 hi0 = *(const uint4*)(mq0 + 8);
        const uint4 lo1 = *(const uint4*)(mq1);
        const uint4 hi1 = *(const uint4*)(mq1 + 8);
        mq0 += mstep; mq1 += mstep;

        if (it < 31) {
            const char* kg = (const char*)kb + (size_t)(kt + 64) * 128;
            const char* vg = (const char*)vb + (size_t)(kt + 64) * 2;
            ld16_lds(kg + (size_t)r0 * 128 + gcc0 * 16, (char*)Ks[nxt] + c0 * 16);
            ld16_lds(kg + (size_t)r1 * 128 + gcc1 * 16, (char*)Ks[nxt] + c1 * 16);
            ld16_lds(vg + (size_t)r0 * 4096 + gcc0 * 16, (char*)Vs[nxt] + c0 * 16);
            ld16_lds(vg + (size_t)r1 * 4096 + gcc1 * 16, (char*)Vs[nxt] + c1 * 16);
        }

        const unsigned short* Kc = Ks[cur];
        const unsigned short* Vc = Vs[cur];

        // ---- S^T = K . Q^T for both groups ----
        f32x4 S0[4], S1[4];
        __builtin_amdgcn_s_setprio(1);
#pragma unroll
        for (int mt = 0; mt < 4; mt++) {
            const unsigned short* kp = Kc + (mt * 16 + l16) * 64;
            bf16x8 ka0 = *(const bf16x8*)&kp[((quad    ) ^ sw) * 8];
            bf16x8 ka1 = *(const bf16x8*)&kp[((4 + quad) ^ sw) * 8];
            f32x4 z0 = (f32x4){0.f,0.f,0.f,0.f};
            f32x4 z1 = (f32x4){0.f,0.f,0.f,0.f};
            z0 = __builtin_amdgcn_mfma_f32_16x16x32_bf16(ka0, qf[0][0], z0, 0, 0, 0);
            S0[mt] = __builtin_amdgcn_mfma_f32_16x16x32_bf16(ka1, qf[0][1], z0, 0, 0, 0);
            z1 = __builtin_amdgcn_mfma_f32_16x16x32_bf16(ka0, qf[1][0], z1, 0, 0, 0);
            S1[mt] = __builtin_amdgcn_mfma_f32_16x16x32_bf16(ka1, qf[1][1], z1, 0, 0, 0);
        }
        __builtin_amdgcn_s_setprio(0);
        // ---- exp2 + pack + and-mask ----
        bf16x4 pf0[4], pf1[4];
#pragma unroll
        for (int mt = 0; mt < 4; mt++) {
            const unsigned int ax0 = (mt == 0) ? lo0.x : (mt == 1) ? lo0.z : (mt == 2) ? hi0.x : hi0.z;
            const unsigned int ay0 = (mt == 0) ? lo0.y : (mt == 1) ? lo0.w : (mt == 2) ? hi0.y : hi0.w;
            const unsigned int ax1 = (mt == 0) ? lo1.x : (mt == 1) ? lo1.z : (mt == 2) ? hi1.x : hi1.z;
            const unsigned int ay1 = (mt == 0) ? lo1.y : (mt == 1) ? lo1.w : (mt == 2) ? hi1.y : hi1.w;
            float p0[4], p1[4];
#pragma unroll
            for (int r = 0; r < 4; r++) {
                p0[r] = __builtin_amdgcn_exp2f(S0[mt][r]);
                p1[r] = __builtin_amdgcn_exp2f(S1[mt][r]);
            }
            uint2 u0, u1;
            u0.x = pkpair(p0[0], p0[1]) & ax0;
            u0.y = pkpair(p0[2], p0[3]) & ay0;
            u1.x = pkpair(p1[0], p1[1]) & ax1;
            u1.y = pkpair(p1[2], p1[3]) & ay1;
            pf0[mt] = __builtin_bit_cast(bf16x4, u0);
            pf1[mt] = __builtin_bit_cast(bf16x4, u1);
        }
        // ---- l += ones . P^T  (MFMA pipe; all rows hold the column sum) ----
        __builtin_amdgcn_s_setprio(1);
#pragma unroll
        for (int mt = 0; mt < 4; mt++) {
            lacc0 = __builtin_amdgcn_mfma_f32_16x16x16bf16_1k(vones, pf0[mt], lacc0, 0, 0, 0);
            lacc1 = __builtin_amdgcn_mfma_f32_16x16x16bf16_1k(vones, pf1[mt], lacc1, 0, 0, 0);
        }
        // ---- O^T += V^T . P^T ----
#pragma unroll
        for (int dvt = 0; dvt < 4; dvt++) {
            const unsigned short* vp = Vc + (dvt * 16 + l16) * 64;
#pragma unroll
            for (int mt = 0; mt < 4; mt++) {
                uint2 vv = *(const uint2*)&vp[((2 * mt + (quad >> 1)) ^ sw) * 8 + (quad & 1) * 4];
                bf16x4 va = __builtin_bit_cast(bf16x4, vv);
                O0[dvt] = __builtin_amdgcn_mfma_f32_16x16x16bf16_1k(va, pf0[mt], O0[dvt], 0, 0, 0);
                O1[dvt] = __builtin_amdgcn_mfma_f32_16x16x16bf16_1k(va, pf1[mt], O1[dvt], 0, 0, 0);
            }
        }
        __builtin_amdgcn_s_setprio(0);
    }
    // ---- epilogue: every lane already holds l(q=l16) in lacc (rows equal) ----
#pragma unroll
    for (int g = 0; g < 2; g++) {
        const float rl = __builtin_amdgcn_rcpf(g ? lacc1[0] : lacc0[0]);
        const f32x4* O = g ? O1 : O0;
#pragma unroll
        for (int dvt = 0; dvt < 4; dvt++) {
            uint2 st;
            st.x = pk2(O[dvt][0] * rl, O[dvt][1] * rl);
            st.y = pk2(O[dvt][2] * rl, O[dvt][3] * rl);
            *(uint2*)&ctx[(size_t)(b * 2048 + qrow[g]) * 1024 + h * 64 + dvt * 16 + quad * 4] = st;
        }
    }
}

// ---------------------------------------------------------------------------
extern "C" void kernel_launch(void* const* d_in, const int* in_sizes, int n_in,
                              void* d_out, int out_size, void* d_ws, size_t ws_size,
                              hipStream_t stream)
{
    const float* Qin = (const float*)d_in[0];
    const float* Kin = (const float*)d_in[1];
    const float* Vin = (const float*)d_in[2];
    const float* Msk = (const float*)d_in[3];
    const float* Wq  = (const float*)d_in[4];
    const float* bq  = (const float*)d_in[5];
    const float* Wk  = (const float*)d_in[6];
    const float* bk  = (const float*)d_in[7];
    const float* Wv  = (const float*)d_in[8];
    const float* bv  = (const float*)d_in[9];
    const float* Wo  = (const float*)d_in[10];
    const float* bo  = (const float*)d_in[11];

    unsigned short* w = (unsigned short*)d_ws;
    unsigned short* wts  = w;                       // 4 x 1M elems (bf16 weights^T)
    unsigned short* wto  = w + 3u * (1u << 20);
    unsigned short* qcv  = w + 4u * (1u << 20);     // bf16 activations, 3 x 8M
    unsigned short* qb   = qcv + 3u * (1u << 23);   // projections, 3 x 8M
    unsigned short* kb   = qb  + (1u << 23);
    unsigned short* vTb  = kb  + (1u << 23);
    unsigned short* ctxb = qcv;                     // alias: qcv dead after qkv_gemm
    unsigned short* m16  = vTb + (1u << 23);        // 4M ushorts = 8 MB tiled and-mask
    // total ws use: 8 MB + 96 MB + 8 MB = 112 MB

    preprocess<<<18432, 256, 0, stream>>>(Qin, Kin, Vin, Msk, Wq, Wk, Wv, Wo,
                                          qcv, m16, wts);
    qkv_gemm<<<dim3(64, 8, 3), 256, 0, stream>>>(qcv, wts, bq, bk, bv, qb);
    attn_kernel<<<1024, 256, 0, stream>>>(qb, kb, vTb, m16, ctxb);
    gemm_final<<<dim3(64, 8), 256, 0, stream>>>(ctxb, wto, bo, (float*)d_out);
}